// Round 19
// baseline (672.184 us; speedup 1.0000x reference)
//
#include <hip/hip_runtime.h>
#include <math.h>

// BracketNet fused: ctx_{s+1} = GELU(Wc·ctx_s + z_s), z_s = b + Wx·x_s,
// out_s = x_s + ctx_{s+1}. ONE kernel, one wave per (b,h) chain.
// The serial engine is r16/r18's readlane+dot2 GEMV (478 cyc/step, best
// measured). The z-GEMV (independent of g) is interleaved into the g-chain's
// ~290 cyc/step of dependency bubbles: 4-deep in-register z ring, z[s+4]
// computed at step s from xb[(i+4)&7] (x pipeline is depth-8). Second pinned
// weight set wpx[32]; x-readlanes split 16+16 across sched regions to cap
// live SGPR temps (~48). 2 vmem/step -> steady vmcnt(6).
//
// Scoreboard (serial-path broadcast, cyc/step): readlane+dot2 478 <
// readlane+fma 535 < bpermute+MFMA 1078 < LDS roundtrip ~1100 (r9/r17).
// r15 law: wall = S x single-wave step latency; only path-shortening or
// bubble-filling helps. This round fills bubbles with pass1's work.

typedef float    f32x4 __attribute__((ext_vector_type(4)));
typedef _Float16 f16x2 __attribute__((ext_vector_type(2)));

#define S_LEN 2048
#define B_SZ  64
#define D_SZ  512
#define DIM   64
#define STRIDE ((size_t)(B_SZ * D_SZ))   // floats between consecutive s

__device__ __forceinline__ int pkrtz(float a, float b) {
    return __builtin_bit_cast(int, __builtin_amdgcn_cvt_pkrtz(a, b));
}

__device__ __forceinline__ float fdot2h(int pack, int wpk, float acc) {
#if __has_builtin(__builtin_amdgcn_fdot2)
    return __builtin_amdgcn_fdot2(__builtin_bit_cast(f16x2, pack),
                                  __builtin_bit_cast(f16x2, wpk), acc, false);
#else
    float d;
    asm("v_dot2_f32_f16 %0, %1, %2, %3"
        : "=v"(d)
        : "v"(__builtin_bit_cast(f16x2, pack)),
          "v"(__builtin_bit_cast(f16x2, wpk)), "v"(acc));
    return d;
#endif
}

// 3-term A&S 7.1.25 erf gelu (|eps|<=2.5e-5), fma-combined tail.
__device__ __forceinline__ float gelu_fast(float y) {
    const float ax = fabsf(y) * 0.70710678118654752440f;
    const float t  = __builtin_amdgcn_rcpf(fmaf(0.47047f, ax, 1.0f));
    const float e  = __builtin_amdgcn_exp2f(-ax * ax * 1.44269504088896f);
    float p = fmaf(0.7478556f, t, -0.0958798f);
    p = fmaf(p, t, 0.3480242f);
    p *= t;
    float er = fmaf(-p, e, 1.0f);
    er = copysignf(er, y);
    const float m = 0.5f * y;
    return fmaf(m, er, m);
}

#define GLOAD(dst, ptr) \
    asm volatile("global_load_dword %0, %1, off" : "=v"(dst) : "v"(ptr))
#define GSTORE(val, ptr) \
    asm volatile("global_store_dword %1, %0, off" : : "v"(val), "v"(ptr) : "memory")

#define RLN(s, l) __builtin_amdgcn_readlane(s, l)

// 32 readlanes of packed pairs (even lanes 0..62) into t[0..31].
#define RLA32(t, s)                                                           \
    t[0]  = RLN(s, 0);  t[1]  = RLN(s, 2);  t[2]  = RLN(s, 4);                \
    t[3]  = RLN(s, 6);  t[4]  = RLN(s, 8);  t[5]  = RLN(s, 10);               \
    t[6]  = RLN(s, 12); t[7]  = RLN(s, 14); t[8]  = RLN(s, 16);               \
    t[9]  = RLN(s, 18); t[10] = RLN(s, 20); t[11] = RLN(s, 22);               \
    t[12] = RLN(s, 24); t[13] = RLN(s, 26); t[14] = RLN(s, 28);               \
    t[15] = RLN(s, 30); t[16] = RLN(s, 32); t[17] = RLN(s, 34);               \
    t[18] = RLN(s, 36); t[19] = RLN(s, 38); t[20] = RLN(s, 40);               \
    t[21] = RLN(s, 42); t[22] = RLN(s, 44); t[23] = RLN(s, 46);               \
    t[24] = RLN(s, 48); t[25] = RLN(s, 50); t[26] = RLN(s, 52);               \
    t[27] = RLN(s, 54); t[28] = RLN(s, 56); t[29] = RLN(s, 58);               \
    t[30] = RLN(s, 60); t[31] = RLN(s, 62)

#define RLA16A(t, s)                                                          \
    t[0]  = RLN(s, 0);  t[1]  = RLN(s, 2);  t[2]  = RLN(s, 4);                \
    t[3]  = RLN(s, 6);  t[4]  = RLN(s, 8);  t[5]  = RLN(s, 10);               \
    t[6]  = RLN(s, 12); t[7]  = RLN(s, 14); t[8]  = RLN(s, 16);               \
    t[9]  = RLN(s, 18); t[10] = RLN(s, 20); t[11] = RLN(s, 22);               \
    t[12] = RLN(s, 24); t[13] = RLN(s, 26); t[14] = RLN(s, 28);               \
    t[15] = RLN(s, 30)

#define RLA16B(t, s)                                                          \
    t[16] = RLN(s, 32); t[17] = RLN(s, 34); t[18] = RLN(s, 36);               \
    t[19] = RLN(s, 38); t[20] = RLN(s, 40); t[21] = RLN(s, 42);               \
    t[22] = RLN(s, 44); t[23] = RLN(s, 46); t[24] = RLN(s, 48);               \
    t[25] = RLN(s, 50); t[26] = RLN(s, 52); t[27] = RLN(s, 54);               \
    t[28] = RLN(s, 56); t[29] = RLN(s, 58); t[30] = RLN(s, 60);               \
    t[31] = RLN(s, 62)

// dots k -> acc k&7; P##0..P##7 accumulators.
#define DOTS32(P, t, wa)                                                      \
    P##0 = fdot2h(t[0],  wa[0],  P##0); P##1 = fdot2h(t[1],  wa[1],  P##1);   \
    P##2 = fdot2h(t[2],  wa[2],  P##2); P##3 = fdot2h(t[3],  wa[3],  P##3);   \
    P##4 = fdot2h(t[4],  wa[4],  P##4); P##5 = fdot2h(t[5],  wa[5],  P##5);   \
    P##6 = fdot2h(t[6],  wa[6],  P##6); P##7 = fdot2h(t[7],  wa[7],  P##7);   \
    P##0 = fdot2h(t[8],  wa[8],  P##0); P##1 = fdot2h(t[9],  wa[9],  P##1);   \
    P##2 = fdot2h(t[10], wa[10], P##2); P##3 = fdot2h(t[11], wa[11], P##3);   \
    P##4 = fdot2h(t[12], wa[12], P##4); P##5 = fdot2h(t[13], wa[13], P##5);   \
    P##6 = fdot2h(t[14], wa[14], P##6); P##7 = fdot2h(t[15], wa[15], P##7);   \
    P##0 = fdot2h(t[16], wa[16], P##0); P##1 = fdot2h(t[17], wa[17], P##1);   \
    P##2 = fdot2h(t[18], wa[18], P##2); P##3 = fdot2h(t[19], wa[19], P##3);   \
    P##4 = fdot2h(t[20], wa[20], P##4); P##5 = fdot2h(t[21], wa[21], P##5);   \
    P##6 = fdot2h(t[22], wa[22], P##6); P##7 = fdot2h(t[23], wa[23], P##7);   \
    P##0 = fdot2h(t[24], wa[24], P##0); P##1 = fdot2h(t[25], wa[25], P##1);   \
    P##2 = fdot2h(t[26], wa[26], P##2); P##3 = fdot2h(t[27], wa[27], P##3);   \
    P##4 = fdot2h(t[28], wa[28], P##4); P##5 = fdot2h(t[29], wa[29], P##5);   \
    P##6 = fdot2h(t[30], wa[30], P##6); P##7 = fdot2h(t[31], wa[31], P##7)

#define DOTS16A(P, t, wa)                                                     \
    P##0 = fdot2h(t[0],  wa[0],  P##0); P##1 = fdot2h(t[1],  wa[1],  P##1);   \
    P##2 = fdot2h(t[2],  wa[2],  P##2); P##3 = fdot2h(t[3],  wa[3],  P##3);   \
    P##4 = fdot2h(t[4],  wa[4],  P##4); P##5 = fdot2h(t[5],  wa[5],  P##5);   \
    P##6 = fdot2h(t[6],  wa[6],  P##6); P##7 = fdot2h(t[7],  wa[7],  P##7);   \
    P##0 = fdot2h(t[8],  wa[8],  P##0); P##1 = fdot2h(t[9],  wa[9],  P##1);   \
    P##2 = fdot2h(t[10], wa[10], P##2); P##3 = fdot2h(t[11], wa[11], P##3);   \
    P##4 = fdot2h(t[12], wa[12], P##4); P##5 = fdot2h(t[13], wa[13], P##5);   \
    P##6 = fdot2h(t[14], wa[14], P##6); P##7 = fdot2h(t[15], wa[15], P##7)

#define DOTS16B(P, t, wa)                                                     \
    P##0 = fdot2h(t[16], wa[16], P##0); P##1 = fdot2h(t[17], wa[17], P##1);   \
    P##2 = fdot2h(t[18], wa[18], P##2); P##3 = fdot2h(t[19], wa[19], P##3);   \
    P##4 = fdot2h(t[20], wa[20], P##4); P##5 = fdot2h(t[21], wa[21], P##5);   \
    P##6 = fdot2h(t[22], wa[22], P##6); P##7 = fdot2h(t[23], wa[23], P##7);   \
    P##0 = fdot2h(t[24], wa[24], P##0); P##1 = fdot2h(t[25], wa[25], P##1);   \
    P##2 = fdot2h(t[26], wa[26], P##2); P##3 = fdot2h(t[27], wa[27], P##3);   \
    P##4 = fdot2h(t[28], wa[28], P##4); P##5 = fdot2h(t[29], wa[29], P##5);   \
    P##6 = fdot2h(t[30], wa[30], P##6); P##7 = fdot2h(t[31], wa[31], P##7)

#define RED8(P) (((P##0 + P##1) + (P##2 + P##3)) + ((P##4 + P##5) + (P##6 + P##7)))

#define PACK_PAIR(dst, val)                                                   \
    const int dst##_i = __float_as_int(val);                                  \
    const int dst##_s = __builtin_amdgcn_mov_dpp(dst##_i, 0x101, 0xf, 0xf, true); \
    const int dst = pkrtz(val, __int_as_float(dst##_s))

__global__ __launch_bounds__(64, 1) void bracket_fused(
    const float* __restrict__ src, const float* __restrict__ W,
    const float* __restrict__ bias, float* __restrict__ out)
{
    const int lane = threadIdx.x;
    const int bb   = blockIdx.x >> 3;
    const int hh   = blockIdx.x & 7;

    // Weight rows (pinned via volatile asm, packed to f16 pairs as ints).
    // Loaded in 8-quad chunks to cap prologue VGPR pressure.
    const float* wbase = W + (size_t)(hh * DIM + lane) * (2 * DIM);
    int wp[32];    // Wc pairs
    int wpx[32];   // Wx pairs
    {
        f32x4 q[8];
#pragma unroll
        for (int c = 0; c < 4; ++c) {   // c: 0,1 = Wc halves; 2,3 = Wx halves
#pragma unroll
            for (int i = 0; i < 8; ++i) {
                const float* pq = wbase + c * 32 + i * 4;
                asm volatile("global_load_dwordx4 %0, %1, off"
                             : "=v"(q[i]) : "v"(pq));
            }
            asm volatile("s_waitcnt vmcnt(0)" ::: "memory");
            __builtin_amdgcn_sched_barrier(0);
            int* dst = (c < 2) ? wp : wpx;
            const int base = (c & 1) * 16;
#pragma unroll
            for (int j = 0; j < 8; ++j) {
                dst[base + 2 * j]     = pkrtz(q[j].x, q[j].y);
                dst[base + 2 * j + 1] = pkrtz(q[j].z, q[j].w);
            }
        }
    }

    const float bv = bias[hh * DIM + lane];

    const float* sp = src + (size_t)bb * D_SZ + hh * DIM + lane;
    float*       op = out + (size_t)bb * D_SZ + hh * DIM + lane;
    const float* px = sp;

    float xb[8];
    float zr0, zr1, zr2, zr3;   // z ring: zr[p] holds z[s] for next use
    float g = 0.0f;             // ctx_0 = 0

    // Prologue: 8 x loads.
#pragma unroll
    for (int i = 0; i < 8; ++i) { GLOAD(xb[i], px); px += STRIDE; }

    // z[0..3] from xb[0..3] (needs first 4 loads -> vmcnt(4)).
    asm volatile("s_waitcnt vmcnt(4)" ::: "memory");
    __builtin_amdgcn_sched_barrier(0);
#define ZFULL(dst, xreg)                                                      \
    do {                                                                      \
        PACK_PAIR(zp_, xreg);                                                 \
        int tz[32];                                                           \
        RLA32(tz, zp_);                                                       \
        __builtin_amdgcn_sched_barrier(0);                                    \
        float c0 = bv, c1 = 0.f, c2 = 0.f, c3 = 0.f;                          \
        float c4 = 0.f, c5 = 0.f, c6 = 0.f, c7 = 0.f;                         \
        DOTS32(c, tz, wpx);                                                   \
        dst = RED8(c);                                                        \
    } while (0)
    ZFULL(zr0, xb[0]); ZFULL(zr1, xb[1]); ZFULL(zr2, xb[2]); ZFULL(zr3, xb[3]);

    // Full step: g-GEMV (serial) + z-GEMV for s+4 (bubble-filler) + store.
#define STEP_FULL(i, p)                                                       \
    do {                                                                      \
        PACK_PAIR(gp_, g);                                                    \
        const float xz_ = xb[((i) + 4) & 7];                                  \
        PACK_PAIR(xp_, xz_);                                                  \
        int tg[32], tx[32];                                                   \
        RLA32(tg, gp_);                                                       \
        __builtin_amdgcn_sched_barrier(0);                                    \
        float a0 = zr##p, a1 = 0.f, a2 = 0.f, a3 = 0.f;                       \
        float a4 = 0.f, a5 = 0.f, a6 = 0.f, a7 = 0.f;                         \
        DOTS32(a, tg, wp);                                                    \
        RLA16A(tx, xp_);                                                      \
        const float y = RED8(a);                                              \
        __builtin_amdgcn_sched_barrier(0);                                    \
        float b0 = bv, b1 = 0.f, b2 = 0.f, b3 = 0.f;                          \
        float b4 = 0.f, b5 = 0.f, b6 = 0.f, b7 = 0.f;                         \
        DOTS16A(b, tx, wpx);                                                  \
        RLA16B(tx, xp_);                                                      \
        g = gelu_fast(y);                                                     \
        __builtin_amdgcn_sched_barrier(0);                                    \
        DOTS16B(b, tx, wpx);                                                  \
        zr##p = RED8(b);                                                      \
        const float r_ = xb[i] + g;                                           \
        GSTORE(r_, op);                                                       \
        op += STRIDE;                                                         \
    } while (0)

    // g-only step (epilogue tail: no z-compute, no load).
#define STEP_G(i, p)                                                          \
    do {                                                                      \
        PACK_PAIR(gp_, g);                                                    \
        int tg[32];                                                           \
        RLA32(tg, gp_);                                                       \
        __builtin_amdgcn_sched_barrier(0);                                    \
        float a0 = zr##p, a1 = 0.f, a2 = 0.f, a3 = 0.f;                       \
        float a4 = 0.f, a5 = 0.f, a6 = 0.f, a7 = 0.f;                         \
        DOTS32(a, tg, wp);                                                    \
        const float y = RED8(a);                                              \
        g = gelu_fast(y);                                                     \
        const float r_ = xb[i] + g;                                           \
        GSTORE(r_, op);                                                       \
        op += STRIDE;                                                         \
    } while (0)

#define STEPL(i, p, N)                                                        \
    do {                                                                      \
        asm volatile("s_waitcnt vmcnt(" #N ")");                              \
        __builtin_amdgcn_sched_barrier(0);                                    \
        STEP_FULL(i, p);                                                      \
        GLOAD(xb[i], px); px += STRIDE;                                       \
    } while (0)

#define STEPZ(i, p, N)                                                        \
    do {                                                                      \
        asm volatile("s_waitcnt vmcnt(" #N ")");                              \
        __builtin_amdgcn_sched_barrier(0);                                    \
        STEP_FULL(i, p);                                                      \
    } while (0)

    // vmcnt accounting, 2 vmem/step (store, x-load):
    // fill: step i needs xb[(i+4)&7]; prologue had 8 loads, no stores.
    STEPL(0, 0, 3); STEPL(1, 1, 4); STEPL(2, 2, 5); STEPL(3, 3, 6);
    STEPL(4, 0, 6); STEPL(5, 1, 6); STEPL(6, 2, 6); STEPL(7, 3, 6);
    // steady: x[s+4] issued 4 steps back; 3 steps x 2 ops after it -> vmcnt(6).
    for (int blk = 0; blk < 254; ++blk) {
        STEPL(0, 0, 6); STEPL(1, 1, 6); STEPL(2, 2, 6); STEPL(3, 3, 6);
        STEPL(4, 0, 6); STEPL(5, 1, 6); STEPL(6, 2, 6); STEPL(7, 3, 6);
    }
    // epilogue s=2040..2043: z-compute for 2044..2047, no loads issued.
    STEPZ(0, 0, 6); STEPZ(1, 1, 5); STEPZ(2, 2, 4); STEPZ(3, 3, 3);
    // s=2044..2047: g-only (all loads complete after e3's vmcnt(3)).
    STEP_G(4, 0); STEP_G(5, 1); STEP_G(6, 2); STEP_G(7, 3);

#undef STEPL
#undef STEPZ
#undef STEP_FULL
#undef STEP_G
#undef ZFULL
}

extern "C" void kernel_launch(void* const* d_in, const int* in_sizes, int n_in,
                              void* d_out, int out_size, void* d_ws, size_t ws_size,
                              hipStream_t stream) {
    const float* src = (const float*)d_in[0];
    const float* W   = (const float*)d_in[1];
    const float* b   = (const float*)d_in[2];
    float* out       = (float*)d_out;

    hipLaunchKernelGGL(bracket_fused, dim3(B_SZ * 8), dim3(64), 0, stream,
                       src, W, b, out);
}